// Round 1
// baseline (92.280 us; speedup 1.0000x reference)
//
#include <hip/hip_runtime.h>

#define NNODES 1024
#define KDIM   128   // input width of both layers
#define HDIM   64
#define NCLS   40

// pooled = relu(X@Wp + bp) [N,128]; s = X@Ws + bs [N,64]
__global__ __launch_bounds__(256) void lin_kernel(
    const float* __restrict__ X, const float* __restrict__ Wp,
    const float* __restrict__ bp, const float* __restrict__ Ws,
    const float* __restrict__ bs, float* __restrict__ pooled,
    float* __restrict__ s)
{
    __shared__ float xT[8][KDIM];
    const int tid = threadIdx.x;
    const int row0 = blockIdx.x * 8;
    for (int i = tid; i < 8 * KDIM; i += 256)
        xT[i >> 7][i & 127] = X[row0 * KDIM + i];
    __syncthreads();

    // 8 rows x 192 cols = 1536 outputs; 192 = 3*64 so every wave is uniform
    // in (row, which-matrix) -> no divergence, coalesced W reads.
    for (int i = tid; i < 8 * 192; i += 256) {
        const int r = i / 192;
        const int j = i - r * 192;
        if (j < 128) {
            float acc = bp[j];
            const float* w = Wp + j;
            #pragma unroll 4
            for (int k = 0; k < KDIM; ++k) acc += xT[r][k] * w[k * 128];
            pooled[(row0 + r) * 128 + j] = fmaxf(acc, 0.f);
        } else {
            const int jj = j - 128;
            float acc = bs[jj];
            const float* w = Ws + jj;
            #pragma unroll 4
            for (int k = 0; k < KDIM; ++k) acc += xT[r][k] * w[k * 64];
            s[(row0 + r) * 64 + jj] = acc;
        }
    }
}

// One block of 128 threads per node v:
//   bitmask of A row -> masked max of pooled rows -> agg
//   h = relu(concat(s[v], agg@Wn + bn)); h /= max(||h||, 1e-12)
//   optional head: out[v] = h@Wh + bh
__global__ __launch_bounds__(128) void agg_kernel(
    const int* __restrict__ A, const float* __restrict__ pooled,
    const float* __restrict__ s, const float* __restrict__ Wn,
    const float* __restrict__ bn, float* __restrict__ h_out,
    const float* __restrict__ Wh, const float* __restrict__ bh,
    float* __restrict__ out)
{
    __shared__ unsigned long long masks[16];
    __shared__ float aggL[128];
    __shared__ float hL[128];
    __shared__ float red[2];

    const int v = blockIdx.x;
    const int d = threadIdx.x;
    const int lane = d & 63;
    const int wave = d >> 6;

    // adjacency bitmask for row v (coalesced scan, ballot-compress)
    const int* Arow = A + v * NNODES;
    for (int c = wave; c < 16; c += 2) {
        unsigned long long m = __ballot(Arow[c * 64 + lane] != 0);
        if (lane == 0) masks[c] = m;
    }
    __syncthreads();

    // masked elementwise max over neighbors
    float acc = -1e30f;
    for (int c = 0; c < 16; ++c) {
        unsigned long long m = masks[c];  // LDS broadcast, wave-uniform
        const float* pbase = pooled + (c * 64) * 128 + d;
        while (m) {
            const int b = __builtin_ctzll(m);
            m &= m - 1;
            acc = fmaxf(acc, pbase[b * 128]);  // coalesced 512B row slice
        }
    }
    const float agg = (acc <= -5e29f) ? 0.f : acc;  // isolated nodes -> 0
    aggL[d] = agg;
    __syncthreads();

    // concat(self-linear, neighbor-linear)
    float val;
    if (d < 64) {
        val = s[v * HDIM + d];
    } else {
        const int j = d - 64;
        float a = bn[j];
        const float* w = Wn + j;
        #pragma unroll 4
        for (int k = 0; k < KDIM; ++k) a += aggL[k] * w[k * 64];
        val = a;
    }
    val = fmaxf(val, 0.f);  // relu over the whole concat

    // row L2 norm over 128 threads (2 waves)
    float ss = val * val;
    #pragma unroll
    for (int off = 32; off >= 1; off >>= 1) ss += __shfl_xor(ss, off, 64);
    if (lane == 0) red[wave] = ss;
    __syncthreads();
    const float nrm = fmaxf(sqrtf(red[0] + red[1]), 1e-12f);
    const float hn = val / nrm;
    h_out[v * 128 + d] = hn;

    if (out) {  // fused classifier head
        hL[d] = hn;
        __syncthreads();
        if (d < NCLS) {
            float o = bh[d];
            #pragma unroll 4
            for (int k = 0; k < KDIM; ++k) o += hL[k] * Wh[k * NCLS + d];
            out[v * NCLS + d] = o;
        }
    }
}

extern "C" void kernel_launch(void* const* d_in, const int* in_sizes, int n_in,
                              void* d_out, int out_size, void* d_ws, size_t ws_size,
                              hipStream_t stream) {
    const float* x   = (const float*)d_in[0];
    const int*   A   = (const int*)  d_in[1];
    const float* Wp1 = (const float*)d_in[2];
    const float* bp1 = (const float*)d_in[3];
    const float* Ws1 = (const float*)d_in[4];
    const float* bs1 = (const float*)d_in[5];
    const float* Wn1 = (const float*)d_in[6];
    const float* bn1 = (const float*)d_in[7];
    const float* Wp2 = (const float*)d_in[8];
    const float* bp2 = (const float*)d_in[9];
    const float* Ws2 = (const float*)d_in[10];
    const float* bs2 = (const float*)d_in[11];
    const float* Wn2 = (const float*)d_in[12];
    const float* bn2 = (const float*)d_in[13];
    const float* Wh  = (const float*)d_in[14];
    const float* bh  = (const float*)d_in[15];
    float* out = (float*)d_out;

    char* ws = (char*)d_ws;
    float* pooled = (float*)(ws);                  // 512 KB
    float* sbuf   = (float*)(ws + (512u << 10));   // 256 KB
    float* h1     = (float*)(ws + (768u << 10));   // 512 KB
    float* h2     = (float*)(ws + (1280u << 10));  // 512 KB

    lin_kernel<<<NNODES / 8, 256, 0, stream>>>(x, Wp1, bp1, Ws1, bs1, pooled, sbuf);
    agg_kernel<<<NNODES, 128, 0, stream>>>(A, pooled, sbuf, Wn1, bn1, h1,
                                           nullptr, nullptr, nullptr);
    lin_kernel<<<NNODES / 8, 256, 0, stream>>>(h1, Wp2, bp2, Ws2, bs2, pooled, sbuf);
    agg_kernel<<<NNODES, 128, 0, stream>>>(A, pooled, sbuf, Wn2, bn2, h2,
                                           Wh, bh, out);
}

// Round 2
// 30.467 us; speedup vs baseline: 3.0289x; 3.0289x over previous
//
#include <hip/hip_runtime.h>

#define NN 1024

// ---------- K1: first linear, 4 rows/block so W is reused 4x ----------
// pooled = relu(X@Wp+bp) [N,128]; s = X@Ws+bs [N,64]
__global__ __launch_bounds__(384) void lin_first(
    const float* __restrict__ X, const float* __restrict__ Wp,
    const float* __restrict__ bp, const float* __restrict__ Ws,
    const float* __restrict__ bs, float* __restrict__ pooled,
    float* __restrict__ sbuf)
{
    __shared__ float xL[4][128];
    __shared__ float lp[2][4][192];
    const int v0 = blockIdx.x * 4;
    const int tid = threadIdx.x;
    for (int i = tid; i < 512; i += 384) xL[i >> 7][i & 127] = X[v0 * 128 + i];
    __syncthreads();
    {
        // 384 threads = 192 outputs x 2 k-halves
        const int kh = (tid >= 192) ? 1 : 0;
        const int j = tid - kh * 192;
        const float* w; int ld;
        if (j < 128) { w = Wp + j;         ld = 128; }
        else         { w = Ws + (j - 128); ld = 64;  }
        float a0 = 0.f, a1 = 0.f, a2 = 0.f, a3 = 0.f;
        const int k0 = kh * 64;
        #pragma unroll 4
        for (int k = 0; k < 64; ++k) {
            const float wv = w[(k0 + k) * ld];
            a0 += xL[0][k0 + k] * wv;  a1 += xL[1][k0 + k] * wv;
            a2 += xL[2][k0 + k] * wv;  a3 += xL[3][k0 + k] * wv;
        }
        lp[kh][0][j] = a0; lp[kh][1][j] = a1; lp[kh][2][j] = a2; lp[kh][3][j] = a3;
    }
    __syncthreads();
    if (tid < 192) {
        #pragma unroll
        for (int r = 0; r < 4; ++r) {
            const float t = lp[0][r][tid] + lp[1][r][tid];
            if (tid < 128) pooled[(v0 + r) * 128 + tid] = fmaxf(t + bp[tid], 0.f);
            else           sbuf[(v0 + r) * 64 + (tid - 128)] = t + bs[tid - 128];
        }
    }
}

// ---------- K2/K3: aggregate + norm + fused next linear (or head) ----------
// One block (512 threads, 8 waves) per node v.
// MODE 0: writes pooled2 = relu(h@Wp2+bp2), s2 = h@Ws2+bs2
// MODE 1: Wp2:=Wh, bp2:=bh; writes outh = h@Wh+bh
template <int MODE>
__global__ __launch_bounds__(512) void agg_kernel(
    const int* __restrict__ A, const float* __restrict__ pooled,
    const float* __restrict__ sbuf,
    const float* __restrict__ Wn, const float* __restrict__ bn,
    const float* __restrict__ Wp2, const float* __restrict__ bp2,
    const float* __restrict__ Ws2, const float* __restrict__ bs2,
    float* __restrict__ out_pooled, float* __restrict__ out_s,
    float* __restrict__ outh)
{
    __shared__ int   nbr[NN];
    __shared__ int   cnt;
    __shared__ float part[4][128];
    __shared__ float aggL[128];
    __shared__ float wpart[4][64];
    __shared__ float hL[128];
    __shared__ float lpart[2][192];
    __shared__ float red[2];

    const int v   = blockIdx.x;
    const int tid = threadIdx.x;
    if (tid == 0) cnt = 0;
    __syncthreads();

    // 1) neighbor list (order-independent: feeds an exact max)
    const int* Arow = A + v * NN;
    for (int i = tid; i < NN; i += 512)
        if (Arow[i]) nbr[atomicAdd(&cnt, 1)] = i;
    __syncthreads();
    const int n = cnt;

    // 2) 4-team strided neighbor max (independent loads, pipelineable)
    const int d    = tid & 127;
    const int team = tid >> 7;
    float acc = -1e30f;
    for (int p = team; p < n; p += 4)
        acc = fmaxf(acc, pooled[nbr[p] * 128 + d]);
    part[team][d] = acc;
    __syncthreads();

    // 3) combine teams; isolated nodes -> 0
    if (team == 0) {
        float m = fmaxf(fmaxf(part[0][d], part[1][d]),
                        fmaxf(part[2][d], part[3][d]));
        aggL[d] = (m <= -5e29f) ? 0.f : m;
    }
    __syncthreads();

    // 4) agg @ Wn with 4-way k-split (threads with d>=64)
    if (d >= 64) {
        const int j = d - 64;
        const float* w = Wn + j;
        const int k0 = team * 32;
        float pv = 0.f;
        #pragma unroll 8
        for (int k = 0; k < 32; ++k) pv += aggL[k0 + k] * w[(k0 + k) * 64];
        wpart[team][j] = pv;
    }
    __syncthreads();

    // 5) concat + relu + L2 normalize (threads 0..127)
    float val = 0.f;
    if (tid < 128) {
        if (d < 64) val = sbuf[v * 64 + d];
        else {
            const int j = d - 64;
            val = bn[j] + wpart[0][j] + wpart[1][j] + wpart[2][j] + wpart[3][j];
        }
        val = fmaxf(val, 0.f);
        float ss = val * val;
        #pragma unroll
        for (int off = 32; off >= 1; off >>= 1) ss += __shfl_xor(ss, off, 64);
        if ((tid & 63) == 0) red[tid >> 6] = ss;
    }
    __syncthreads();
    if (tid < 128) {
        const float nrm = fmaxf(sqrtf(red[0] + red[1]), 1e-12f);
        hL[tid] = val / nrm;
    }
    __syncthreads();

    // 6) fused next-layer linear / classifier head
    if (MODE == 0) {
        if (tid < 384) {  // 192 outputs x 2 k-halves
            const int kh = (tid >= 192) ? 1 : 0;
            const int j  = tid - kh * 192;
            const float* w; int ld;
            if (j < 128) { w = Wp2 + j;         ld = 128; }
            else         { w = Ws2 + (j - 128); ld = 64;  }
            float a = 0.f;
            const int k0 = kh * 64;
            #pragma unroll 4
            for (int k = 0; k < 64; ++k) a += hL[k0 + k] * w[(k0 + k) * ld];
            lpart[kh][j] = a;
        }
        __syncthreads();
        if (tid < 192) {
            const float r = lpart[0][tid] + lpart[1][tid];
            if (tid < 128) out_pooled[v * 128 + tid] = fmaxf(r + bp2[tid], 0.f);
            else           out_s[v * 64 + (tid - 128)] = r + bs2[tid - 128];
        }
    } else {
        // head: 40 outputs x 2 k-halves (waves 0 and 4)
        if (tid < 64 || (tid >= 256 && tid < 320)) {
            const int kh = (tid >= 256) ? 1 : 0;
            const int j  = tid - kh * 256;
            if (j < 40) {
                float a = 0.f;
                const int k0 = kh * 64;
                #pragma unroll 4
                for (int k = 0; k < 64; ++k) a += hL[k0 + k] * Wp2[(k0 + k) * 40 + j];
                lpart[kh][j] = a;
            }
        }
        __syncthreads();
        if (tid < 40) outh[v * 40 + tid] = bp2[tid] + lpart[0][tid] + lpart[1][tid];
    }
}

extern "C" void kernel_launch(void* const* d_in, const int* in_sizes, int n_in,
                              void* d_out, int out_size, void* d_ws, size_t ws_size,
                              hipStream_t stream) {
    const float* x   = (const float*)d_in[0];
    const int*   A   = (const int*)  d_in[1];
    const float* Wp1 = (const float*)d_in[2];
    const float* bp1 = (const float*)d_in[3];
    const float* Ws1 = (const float*)d_in[4];
    const float* bs1 = (const float*)d_in[5];
    const float* Wn1 = (const float*)d_in[6];
    const float* bn1 = (const float*)d_in[7];
    const float* Wp2 = (const float*)d_in[8];
    const float* bp2 = (const float*)d_in[9];
    const float* Ws2 = (const float*)d_in[10];
    const float* bs2 = (const float*)d_in[11];
    const float* Wn2 = (const float*)d_in[12];
    const float* bn2 = (const float*)d_in[13];
    const float* Wh  = (const float*)d_in[14];
    const float* bh  = (const float*)d_in[15];
    float* out = (float*)d_out;

    char* ws = (char*)d_ws;
    float* pooled1 = (float*)(ws);                  // 512 KB
    float* s1      = (float*)(ws + (512u << 10));   // 256 KB
    float* pooled2 = (float*)(ws + (768u << 10));   // 512 KB
    float* s2      = (float*)(ws + (1280u << 10));  // 256 KB

    lin_first<<<NN / 4, 384, 0, stream>>>(x, Wp1, bp1, Ws1, bs1, pooled1, s1);
    agg_kernel<0><<<NN, 512, 0, stream>>>(A, pooled1, s1, Wn1, bn1,
                                          Wp2, bp2, Ws2, bs2,
                                          pooled2, s2, nullptr);
    agg_kernel<1><<<NN, 512, 0, stream>>>(A, pooled2, s2, Wn2, bn2,
                                          Wh, bh, nullptr, nullptr,
                                          nullptr, nullptr, out);
}

// Round 5
// 28.845 us; speedup vs baseline: 3.1992x; 1.0562x over previous
//
#include <hip/hip_runtime.h>

#define NN 1024

// ---------- K1: first linear, 4 rows/block so W is reused 4x ----------
// pooled = relu(X@Wp+bp) [N,128]; s = X@Ws+bs [N,64]
__global__ __launch_bounds__(384) void lin_first(
    const float* __restrict__ X, const float* __restrict__ Wp,
    const float* __restrict__ bp, const float* __restrict__ Ws,
    const float* __restrict__ bs, float* __restrict__ pooled,
    float* __restrict__ sbuf)
{
    __shared__ float xL[4][128];
    __shared__ float lp[2][4][192];
    const int v0 = blockIdx.x * 4;
    const int tid = threadIdx.x;
    for (int i = tid; i < 512; i += 384) xL[i >> 7][i & 127] = X[v0 * 128 + i];
    __syncthreads();
    {
        const int kh = (tid >= 192) ? 1 : 0;
        const int j = tid - kh * 192;
        const float* w; int ld;
        if (j < 128) { w = Wp + j;         ld = 128; }
        else         { w = Ws + (j - 128); ld = 64;  }
        float a0 = 0.f, a1 = 0.f, a2 = 0.f, a3 = 0.f;
        const int k0 = kh * 64;
        #pragma unroll 4
        for (int k = 0; k < 64; ++k) {
            const float wv = w[(k0 + k) * ld];
            a0 += xL[0][k0 + k] * wv;  a1 += xL[1][k0 + k] * wv;
            a2 += xL[2][k0 + k] * wv;  a3 += xL[3][k0 + k] * wv;
        }
        lp[kh][0][j] = a0; lp[kh][1][j] = a1; lp[kh][2][j] = a2; lp[kh][3][j] = a3;
    }
    __syncthreads();
    if (tid < 192) {
        #pragma unroll
        for (int r = 0; r < 4; ++r) {
            const float t = lp[0][r][tid] + lp[1][r][tid];
            if (tid < 128) pooled[(v0 + r) * 128 + tid] = fmaxf(t + bp[tid], 0.f);
            else           sbuf[(v0 + r) * 64 + (tid - 128)] = t + bs[tid - 128];
        }
    }
}

// ---------- K2/K3: aggregate + norm + fused next linear (or head) ----------
// One block (512 threads, 8 waves) per node v. No atomics, no grid sync.
// MODE 0: writes pooled2 = relu(h@Wp2+bp2), s2 = h@Ws2+bs2
// MODE 1: Wp2:=Wh, bp2:=bh; writes outh = h@Wh+bh
template <int MODE>
__global__ __launch_bounds__(512) void agg_kernel(
    const int* __restrict__ A, const float* __restrict__ pooled,
    const float* __restrict__ sbuf,
    const float* __restrict__ Wn, const float* __restrict__ bn,
    const float* __restrict__ Wp2, const float* __restrict__ bp2,
    const float* __restrict__ Ws2, const float* __restrict__ bs2,
    float* __restrict__ out_pooled, float* __restrict__ out_s,
    float* __restrict__ outh)
{
    __shared__ unsigned long long masks[16];
    __shared__ int pfx[16];
    __shared__ int cntS;
    __shared__ int nbr[NN];
    __shared__ float part[4][128];
    __shared__ float aggL[128];
    __shared__ float wpart[4][64];
    __shared__ float hL[128];
    __shared__ float lpart[2][192];
    __shared__ float red[2];

    const int v    = blockIdx.x;
    const int tid  = threadIdx.x;
    const int lane = tid & 63;
    const int wv   = tid >> 6;   // wave 0..7

    // 1) adjacency bitmask via ballot (each wave: 2 chunks of 64 cols)
    const int* Arow = A + v * NN;
    #pragma unroll
    for (int i = 0; i < 2; ++i) {
        const int c = wv * 2 + i;
        const unsigned long long m = __ballot(Arow[c * 64 + lane] != 0);
        if (lane == 0) masks[c] = m;
    }
    __syncthreads();
    // 2) serial prefix over 16 chunk-popcounts (thread 0; ~16 cheap steps)
    if (tid == 0) {
        int off = 0;
        #pragma unroll
        for (int c = 0; c < 16; ++c) { pfx[c] = off; off += __popcll(masks[c]); }
        cntS = off;
    }
    __syncthreads();
    // 3) compaction: every set bit knows its output slot (deterministic)
    #pragma unroll
    for (int i = 0; i < 2; ++i) {
        const int c = wv * 2 + i;
        const unsigned long long m = masks[c];
        if ((m >> lane) & 1ull) {
            const int pos = pfx[c] + __popcll(m & ((1ull << lane) - 1ull));
            nbr[pos] = c * 64 + lane;
        }
    }
    __syncthreads();
    const int n = cntS;

    // 4) 4-team gather-max, 4-way unrolled (4 independent loads in flight)
    const int d    = tid & 127;
    const int team = tid >> 7;
    float a0 = -1e30f, a1 = -1e30f, a2 = -1e30f, a3 = -1e30f;
    int p = team;
    for (; p + 12 < n; p += 16) {
        a0 = fmaxf(a0, pooled[nbr[p]      * 128 + d]);
        a1 = fmaxf(a1, pooled[nbr[p + 4]  * 128 + d]);
        a2 = fmaxf(a2, pooled[nbr[p + 8]  * 128 + d]);
        a3 = fmaxf(a3, pooled[nbr[p + 12] * 128 + d]);
    }
    for (; p < n; p += 4) a0 = fmaxf(a0, pooled[nbr[p] * 128 + d]);
    part[team][d] = fmaxf(fmaxf(a0, a1), fmaxf(a2, a3));
    __syncthreads();

    // 5) combine teams; isolated nodes -> 0
    if (team == 0) {
        const float m = fmaxf(fmaxf(part[0][d], part[1][d]),
                              fmaxf(part[2][d], part[3][d]));
        aggL[d] = (m <= -5e29f) ? 0.f : m;
    }
    __syncthreads();

    // 6) agg @ Wn with 4-way k-split (threads with d>=64)
    if (d >= 64) {
        const int j = d - 64;
        const float* w = Wn + j;
        const int k0 = team * 32;
        float pv = 0.f;
        #pragma unroll 8
        for (int k = 0; k < 32; ++k) pv += aggL[k0 + k] * w[(k0 + k) * 64];
        wpart[team][j] = pv;
    }
    __syncthreads();

    // 7) concat + relu + L2 normalize (threads 0..127)
    float val = 0.f;
    if (tid < 128) {
        if (d < 64) val = sbuf[v * 64 + d];
        else {
            const int j = d - 64;
            val = bn[j] + wpart[0][j] + wpart[1][j] + wpart[2][j] + wpart[3][j];
        }
        val = fmaxf(val, 0.f);
        float ss = val * val;
        #pragma unroll
        for (int off = 32; off >= 1; off >>= 1) ss += __shfl_xor(ss, off, 64);
        if ((tid & 63) == 0) red[tid >> 6] = ss;
    }
    __syncthreads();
    if (tid < 128) {
        const float nrm = fmaxf(sqrtf(red[0] + red[1]), 1e-12f);
        hL[tid] = val / nrm;
    }
    __syncthreads();

    // 8) fused next-layer linear / classifier head
    if (MODE == 0) {
        if (tid < 384) {  // 192 outputs x 2 k-halves
            const int kh = (tid >= 192) ? 1 : 0;
            const int j  = tid - kh * 192;
            const float* w; int ld;
            if (j < 128) { w = Wp2 + j;         ld = 128; }
            else         { w = Ws2 + (j - 128); ld = 64;  }
            float a = 0.f;
            const int k0 = kh * 64;
            #pragma unroll 4
            for (int k = 0; k < 64; ++k) a += hL[k0 + k] * w[(k0 + k) * ld];
            lpart[kh][j] = a;
        }
        __syncthreads();
        if (tid < 192) {
            const float r = lpart[0][tid] + lpart[1][tid];
            if (tid < 128) out_pooled[v * 128 + tid] = fmaxf(r + bp2[tid], 0.f);
            else           out_s[v * 64 + (tid - 128)] = r + bs2[tid - 128];
        }
    } else {
        // head: 40 outputs x 2 k-halves (waves 0 and 4)
        if (tid < 64 || (tid >= 256 && tid < 320)) {
            const int kh = (tid >= 256) ? 1 : 0;
            const int j  = tid - kh * 256;
            if (j < 40) {
                float a = 0.f;
                const int k0 = kh * 64;
                #pragma unroll 4
                for (int k = 0; k < 64; ++k) a += hL[k0 + k] * Wp2[(k0 + k) * 40 + j];
                lpart[kh][j] = a;
            }
        }
        __syncthreads();
        if (tid < 40) outh[v * 40 + tid] = bp2[tid] + lpart[0][tid] + lpart[1][tid];
    }
}

extern "C" void kernel_launch(void* const* d_in, const int* in_sizes, int n_in,
                              void* d_out, int out_size, void* d_ws, size_t ws_size,
                              hipStream_t stream) {
    const float* x   = (const float*)d_in[0];
    const int*   A   = (const int*)  d_in[1];
    const float* Wp1 = (const float*)d_in[2];
    const float* bp1 = (const float*)d_in[3];
    const float* Ws1 = (const float*)d_in[4];
    const float* bs1 = (const float*)d_in[5];
    const float* Wn1 = (const float*)d_in[6];
    const float* bn1 = (const float*)d_in[7];
    const float* Wp2 = (const float*)d_in[8];
    const float* bp2 = (const float*)d_in[9];
    const float* Ws2 = (const float*)d_in[10];
    const float* bs2 = (const float*)d_in[11];
    const float* Wn2 = (const float*)d_in[12];
    const float* bn2 = (const float*)d_in[13];
    const float* Wh  = (const float*)d_in[14];
    const float* bh  = (const float*)d_in[15];
    float* out = (float*)d_out;

    char* ws = (char*)d_ws;
    float* pooled1 = (float*)(ws);                  // 512 KB
    float* s1      = (float*)(ws + (512u << 10));   // 256 KB
    float* pooled2 = (float*)(ws + (768u << 10));   // 512 KB
    float* s2      = (float*)(ws + (1280u << 10));  // 256 KB

    lin_first<<<NN / 4, 384, 0, stream>>>(x, Wp1, bp1, Ws1, bs1, pooled1, s1);
    agg_kernel<0><<<NN, 512, 0, stream>>>(A, pooled1, s1, Wn1, bn1,
                                          Wp2, bp2, Ws2, bs2,
                                          pooled2, s2, nullptr);
    agg_kernel<1><<<NN, 512, 0, stream>>>(A, pooled2, s2, Wn2, bn2,
                                          Wh, bh, nullptr, nullptr,
                                          nullptr, nullptr, out);
}